// Round 4
// baseline (499.173 us; speedup 1.0000x reference)
//
#include <hip/hip_runtime.h>
#include <hip/hip_bf16.h>

// O[b,i,h,p] = sum_{c=l*3+j in 768, tap in 3} W[l,j,tap,i] * S_{b,h}[c][p+tap]
// S[c][t]: t=0,8,9 -> 0; t=(w+1)%7+1 <- V[c][w]
// V[c][w] = x[b,l,r1,w]*[0<=r1<7] + x[b,256+l,r2,w]*[0<=r2<7],
//   r1 = h+j-1, r2 = ((h+6)%7)+j-1            (verified rounds 1-3)
//
// Round 4: (a) prep_v2 = coalesced Vt builder (LDS-staged x rows, linear bf16x8
// stores); (b) gemm_vt2 = 128-thread blocks, 2 waves x (64M x 128N) tiles ->
// wave FLOP/LDS-byte 32 -> 42.7, 4 blocks/CU.

typedef __bf16 bf16x8 __attribute__((ext_vector_type(8)));
typedef float f32x4 __attribute__((ext_vector_type(4)));

#define VT_OFFSET (4u << 20)                       // W2 at d_ws+0, Vt at d_ws+4MB
#define VT_BYTES  (7168ull * 7 * 768 * 2)          // 77,070,336
#define WS_NEED   (VT_OFFSET + VT_BYTES)

__global__ __launch_bounds__(256) void prep_w(const float* __restrict__ Wg,
                                              __bf16* __restrict__ W2) {
    int idx = blockIdx.x * 256 + threadIdx.x;      // over 512*2304
    int i = idx / 2304;
    int kk = idx - i * 2304;
    int tap = kk / 768;
    int c = kk - tap * 768;
    W2[idx] = (__bf16)Wg[(c * 3 + tap) * 512 + i];
}

// Block per (b,h). Stage x rows h+j-1 (half A) and hm+j-1 (half B) into LDS
// (zero-filled when out of range), then write Vt[bh][r][c] as linear 16B stores.
// Vt[bh][r][c=3l+j] = XA[j][l][(r+6)%7] + XB[j][l][(r+6)%7].
__global__ __launch_bounds__(256) void prep_v2(const float* __restrict__ x,
                                               __bf16* __restrict__ Vt) {
    __shared__ float XA[3][256][8];
    __shared__ float XB[3][256][8];
    const int tid = threadIdx.x;
    const int bh = blockIdx.x;
    const int b = bh / 7, h = bh - 7 * b;
    const int hm = (h + 6) % 7;

    #pragma unroll
    for (int jr = 0; jr < 3; ++jr) {
        const int ra = h + jr - 1;
        if (ra >= 0 && ra < 7) {
            const float* src = x + (((size_t)b * 512) * 7 + ra) * 7;
            #pragma unroll
            for (int it = 0; it < 7; ++it) {       // 1792 dwords, coalesced-ish
                const int idx = it * 256 + tid;
                const int l = idx / 7, w = idx - 7 * l;
                XA[jr][l][w] = src[l * 49 + w];
            }
        } else {
            #pragma unroll
            for (int it = 0; it < 8; ++it)
                ((float*)XA[jr])[it * 256 + tid] = 0.f;
        }
        const int rb = hm + jr - 1;
        if (rb >= 0 && rb < 7) {
            const float* src = x + (((size_t)b * 512 + 256) * 7 + rb) * 7;
            #pragma unroll
            for (int it = 0; it < 7; ++it) {
                const int idx = it * 256 + tid;
                const int l = idx / 7, w = idx - 7 * l;
                XB[jr][l][w] = src[l * 49 + w];
            }
        } else {
            #pragma unroll
            for (int it = 0; it < 8; ++it)
                ((float*)XB[jr])[it * 256 + tid] = 0.f;
        }
    }
    __syncthreads();

    // 7 r-rows x 768 c = 5376 bf16 = 672 x 16B units, linear in u.
    #pragma unroll
    for (int it = 0; it < 3; ++it) {
        const int u = it * 256 + tid;
        if (u < 672) {
            const int r = u / 96, cu = u - 96 * r;
            const int w = (r + 6) % 7;
            bf16x8 v;
            #pragma unroll
            for (int e = 0; e < 8; ++e) {
                const int c = cu * 8 + e;
                const int l = c / 3, j = c - 3 * l;
                v[e] = (__bf16)(XA[j][l][w] + XB[j][l][w]);
            }
            *(bf16x8*)(Vt + (size_t)bh * 5376 + u * 8) = v;
        }
    }
}

// 128 threads = 2 waves, block tile 128M x 128N, wave tile 64M x 128N
// (4 M-frags x 8 N-frags of 16x16x32).
__global__ __launch_bounds__(128, 2) void gemm_vt2(const __bf16* __restrict__ Vt,
                                                   const __bf16* __restrict__ W2,
                                                   float* __restrict__ out) {
    __shared__ __bf16 T[16 * 400];       // [bh16][t10][c32], t-stride 40 bf16
    __shared__ __bf16 Bt[128 * 104];     // [n128][tap*32+c], row stride 104 bf16

    const int tid = threadIdx.x;
    // XCD swizzle: 4 N-siblings of one mb are g, g+8, g+16, g+24 -> same XCD
    const int g0 = blockIdx.x;
    const int nb = (g0 >> 3) & 3;
    const int mb = ((g0 >> 5) << 3) | (g0 & 7);
    const int i0 = nb * 128;

    // zero T once (rows t=0,8,9 stay zero; rows 1..7 re-staged per chunk)
    for (int q = tid; q < 3200; q += 128) ((int*)T)[q] = 0;

    const int lane = tid & 63;
    const int wave = tid >> 6;           // 2 waves split on M
    const int ln15 = lane & 15;
    const int gq = lane >> 4;

    f32x4 acc[4][8];
    #pragma unroll
    for (int a = 0; a < 4; ++a)
        #pragma unroll
        for (int bq = 0; bq < 8; ++bq) acc[a][bq] = (f32x4){0.f, 0.f, 0.f, 0.f};

    __syncthreads();                     // T zeroing complete before staging

    for (int chunk = 0; chunk < 24; ++chunk) {
        // ---- stage T: 448 16B units (16 bh x 7 t x 4 q) ----
        #pragma unroll
        for (int it = 0; it < 4; ++it) {
            const int u = it * 128 + tid;
            if (u < 448) {
                const int q = u & 3;
                const int tmp = u >> 2;          // 0..111
                const int t = tmp % 7;
                const int bh = tmp / 7;
                const float4 val = *(const float4*)(
                    Vt + (size_t)((mb * 16 + bh) * 7 + t) * 768 + chunk * 32 + q * 8);
                *(float4*)(&T[bh * 400 + (t + 1) * 40 + q * 8]) = val;
            }
        }
        // ---- stage Bt: 1536 16B units, 12 per thread (q-fastest: coalesced) ----
        #pragma unroll
        for (int it = 0; it < 12; ++it) {
            const int u = it * 128 + tid;        // u = tap*512 + n*4 + q
            const int tap = u >> 9;
            const int rem = u & 511;
            const int n = rem >> 2;
            const int q = rem & 3;
            const float4 val = *(const float4*)(W2 + (size_t)(i0 + n) * 2304 +
                                                tap * 768 + chunk * 32 + q * 8);
            *(float4*)(&Bt[n * 104 + tap * 32 + q * 8]) = val;
        }

        __syncthreads();

        // ---- MFMA: 3 taps x (4 Mfrag x 8 Nfrag) per wave ----
        #pragma unroll
        for (int tap = 0; tap < 3; ++tap) {
            bf16x8 af[4], bfr[8];
            #pragma unroll
            for (int mf = 0; mf < 4; ++mf) {
                const int bh_l = wave * 8 + mf * 2 + (ln15 >> 3);
                const int p = ln15 & 7;
                af[mf] = *(const bf16x8*)(&T[(bh_l * 10 + p + tap) * 40 + gq * 8]);
            }
            #pragma unroll
            for (int nf = 0; nf < 8; ++nf) {
                const int n_l = nf * 16 + ln15;
                bfr[nf] = *(const bf16x8*)(&Bt[n_l * 104 + tap * 32 + gq * 8]);
            }
            #pragma unroll
            for (int mf = 0; mf < 4; ++mf)
                #pragma unroll
                for (int nf = 0; nf < 8; ++nf)
                    acc[mf][nf] = __builtin_amdgcn_mfma_f32_16x16x32_bf16(
                        af[mf], bfr[nf], acc[mf][nf], 0, 0, 0);
        }

        __syncthreads();
    }

    // ---- epilogue: D row = gq*4+reg, col = ln15 ----
    #pragma unroll
    for (int mf = 0; mf < 4; ++mf) {
        #pragma unroll
        for (int r = 0; r < 4; ++r) {
            const int mrow = gq * 4 + r;                 // 0..15
            const int Mg_l = wave * 64 + mf * 16 + mrow;
            const int p = Mg_l & 7;
            if (p == 7) continue;                        // padded row
            const int bh_l = Mg_l >> 3;
            const int bhg = mb * 16 + bh_l;
            const int b = bhg / 7;
            const int h = bhg - 7 * b;
            #pragma unroll
            for (int nf = 0; nf < 8; ++nf) {
                const int i = i0 + nf * 16 + ln15;
                out[(((size_t)b * 512 + i) * 7 + h) * 7 + p] = acc[mf][nf][r];
            }
        }
    }
}

extern "C" void kernel_launch(void* const* d_in, const int* in_sizes, int n_in,
                              void* d_out, int out_size, void* d_ws, size_t ws_size,
                              hipStream_t stream) {
    const float* x  = (const float*)d_in[0];   // (1024,512,7,7) fp32
    const float* Wg = (const float*)d_in[1];   // (256,3,3,512) fp32
    float* out = (float*)d_out;                // (1024,512,7,7) fp32
    __bf16* W2 = (__bf16*)d_ws;                // 512*2304 bf16 = 2.36 MB
    __bf16* Vt = (__bf16*)((char*)d_ws + VT_OFFSET);

    prep_w<<<dim3(512 * 2304 / 256), dim3(256), 0, stream>>>(Wg, W2);
    prep_v2<<<dim3(7168), dim3(256), 0, stream>>>(x, Vt);
    gemm_vt2<<<dim3(448 * 4), dim3(128), 0, stream>>>(Vt, W2, out);
}

// Round 5
// 433.210 us; speedup vs baseline: 1.1523x; 1.1523x over previous
//
#include <hip/hip_runtime.h>
#include <hip/hip_bf16.h>

// O[b,i,h,p] = sum_{c=l*3+j in 768, tap in 3} W[l,j,tap,i] * S_{b,h}[c][p+tap]
// S[c][t]: t=0,8,9 -> 0; t=(w+1)%7+1 <- V[c][w]
// V[c][w] = x[b,l,r1,w]*[0<=r1<7] + x[b,256+l,r2,w]*[0<=r2<7],
//   r1 = h+j-1, r2 = ((h+6)%7)+j-1            (verified rounds 1-4)
//
// Round 5:
//  - W3 = W pre-swizzled into MFMA B-fragment order -> gemm loads B via
//    coalesced global_load_dwordx4, no LDS staging, no barrier coupling.
//  - T staged via register prefetch issued AFTER barrier B so the vmcnt(0)
//    drain at barrier A lands one full MFMA phase later.
//  - prep_vb: block per b, x[b] staged once in 50 KB bf16 LDS, Vt emitted
//    as linear 16B stores (x read exactly once, fully coalesced).

typedef __bf16 bf16x8 __attribute__((ext_vector_type(8)));
typedef __bf16 bf16x4 __attribute__((ext_vector_type(4)));
typedef float f32x4 __attribute__((ext_vector_type(4)));

#define VT_OFFSET (4u << 20)                       // W3 at d_ws+0, Vt at d_ws+4MB
#define VT_BYTES  (7168ull * 7 * 768 * 2)          // 77,070,336

// W3[frag][lane][e], frag = ((nb*8+nf)*3+tap)*24 + chunk  (2304 frags x 1KB)
// element (lane,e) = W[l,j,tap, i0+nf*16+(lane&15)] with c=chunk*32+(lane>>4)*8+e
__global__ __launch_bounds__(256) void prep_w3(const float* __restrict__ Wg,
                                               __bf16* __restrict__ W3) {
    const int u = blockIdx.x * 256 + threadIdx.x;  // 147456 units of 8 bf16
    const int lane = u & 63;
    const int frag = u >> 6;
    const int chunk = frag % 24;
    const int t1 = frag / 24;
    const int tap = t1 % 3;
    const int t2 = t1 / 3;                         // nb*8+nf
    const int i = (t2 >> 3) * 128 + (t2 & 7) * 16 + (lane & 15);
    const int c0 = chunk * 32 + (lane >> 4) * 8;
    bf16x8 v;
    #pragma unroll
    for (int e = 0; e < 8; ++e)
        v[e] = (__bf16)Wg[(size_t)((c0 + e) * 3 + tap) * 512 + i];
    *(bf16x8*)(W3 + (size_t)u * 8) = v;
}

// Block per b: stage x[b] (512x49) as bf16 in LDS, emit Vt for all 7 h.
__global__ __launch_bounds__(256) void prep_vb(const float* __restrict__ x,
                                               __bf16* __restrict__ Vt) {
    __shared__ __bf16 XL[25088];                   // 50.2 KB
    const int tid = threadIdx.x;
    const int b = blockIdx.x;
    const float* src = x + (size_t)b * 25088;

    for (int it = 0; it < 25; ++it) {              // 6272 float4 units
        const int u = it * 256 + tid;
        if (u < 6272) {
            const float4 v = ((const float4*)src)[u];
            bf16x4 o;
            o[0] = (__bf16)v.x; o[1] = (__bf16)v.y;
            o[2] = (__bf16)v.z; o[3] = (__bf16)v.w;
            *(bf16x4*)(&XL[u * 4]) = o;
        }
    }
    __syncthreads();

    #pragma unroll
    for (int it = 0; it < 3; ++it) {
        const int u = it * 256 + tid;              // 672 16B units per h
        if (u < 672) {
            const int r = u / 96, cu = u - 96 * r;
            const int w = (r + 6) % 7;
            for (int h = 0; h < 7; ++h) {
                const int hm = (h + 6) % 7;
                bf16x8 v;
                #pragma unroll
                for (int e = 0; e < 8; ++e) {
                    const int c = cu * 8 + e;
                    const int l = c / 3, j = c - 3 * l;
                    const int r1 = h + j - 1, r2 = hm + j - 1;
                    float s = 0.f;
                    if (r1 >= 0 && r1 < 7) s += (float)XL[l * 49 + r1 * 7 + w];
                    if (r2 >= 0 && r2 < 7) s += (float)XL[(256 + l) * 49 + r2 * 7 + w];
                    v[e] = (__bf16)s;
                }
                *(bf16x8*)(Vt + (size_t)(b * 7 + h) * 5376 + u * 8) = v;
            }
        }
    }
}

// 128 threads = 2 waves, block 128M x 128N, wave 64M x 128N (4 mf x 8 nf).
// LDS = T only (12.8 KB). B direct from W3 (global, frag-ordered, L2-hot).
__global__ __launch_bounds__(128, 2) void gemm_vt3(const __bf16* __restrict__ Vt,
                                                   const __bf16* __restrict__ W3,
                                                   float* __restrict__ out) {
    __shared__ __bf16 T[16 * 400];       // [bh16][t10][c32], t-stride 40 bf16

    const int tid = threadIdx.x;
    // XCD swizzle: 4 N-siblings of one mb land on the same XCD (share Vt slice)
    const int g0 = blockIdx.x;
    const int nb = (g0 >> 3) & 3;
    const int mb = ((g0 >> 5) << 3) | (g0 & 7);

    for (int q = tid; q < 3200; q += 128) ((int*)T)[q] = 0;

    const int lane = tid & 63;
    const int wave = tid >> 6;
    const int ln15 = lane & 15;
    const int gq = lane >> 4;

    // ---- per-thread T-staging decode (u = it*128 + tid over 448 units) ----
    int tu_off[4];
    const __bf16* tsrc[4];
    #pragma unroll
    for (int it = 0; it < 4; ++it) {
        const int u = it * 128 + tid;
        const int q = u & 3, tmp = u >> 2;
        const int t = tmp % 7, bh = tmp / 7;
        tu_off[it] = bh * 400 + (t + 1) * 40 + q * 8;
        tsrc[it] = Vt + (size_t)((mb * 16 + bh) * 7 + t) * 768 + q * 8;
    }
    const bool t3v = (tid < 64);         // it==3 valid iff u < 448

    // ---- A-frag / B-frag address bases ----
    int af_base[4];
    #pragma unroll
    for (int mf = 0; mf < 4; ++mf) {
        const int bh_l = wave * 8 + mf * 2 + (ln15 >> 3);
        const int p = ln15 & 7;
        af_base[mf] = (bh_l * 10 + p) * 40 + gq * 8;
    }
    const __bf16* bsrc[8];
    #pragma unroll
    for (int nf = 0; nf < 8; ++nf)
        bsrc[nf] = W3 + ((size_t)((nb * 8 + nf) * 3 * 24) << 9) + lane * 8;

    f32x4 acc[4][8];
    #pragma unroll
    for (int a = 0; a < 4; ++a)
        #pragma unroll
        for (int bq = 0; bq < 8; ++bq) acc[a][bq] = (f32x4){0.f, 0.f, 0.f, 0.f};

    float4 tr[4];
    #pragma unroll
    for (int it = 0; it < 3; ++it) tr[it] = *(const float4*)(tsrc[it]);
    if (t3v) tr[3] = *(const float4*)(tsrc[3]);

    for (int chunk = 0; chunk < 24; ++chunk) {
        __syncthreads();                 // A: prev MFMA reads done; tr loads drained
        #pragma unroll
        for (int it = 0; it < 3; ++it) *(float4*)(&T[tu_off[it]]) = tr[it];
        if (t3v) *(float4*)(&T[tu_off[3]]) = tr[3];
        __syncthreads();                 // B: T ready (cheap: nothing in flight)

        if (chunk < 23) {                // prefetch chunk+1 AFTER barrier B
            const int co = (chunk + 1) * 32;
            #pragma unroll
            for (int it = 0; it < 3; ++it) tr[it] = *(const float4*)(tsrc[it] + co);
            if (t3v) tr[3] = *(const float4*)(tsrc[3] + co);
        }

        #pragma unroll
        for (int tap = 0; tap < 3; ++tap) {
            bf16x8 af[4], bfr[8];
            const size_t boff = ((size_t)(tap * 24 + chunk) << 9);
            #pragma unroll
            for (int nf = 0; nf < 8; ++nf)
                bfr[nf] = *(const bf16x8*)(bsrc[nf] + boff);
            #pragma unroll
            for (int mf = 0; mf < 4; ++mf)
                af[mf] = *(const bf16x8*)(&T[af_base[mf] + tap * 40]);
            #pragma unroll
            for (int mf = 0; mf < 4; ++mf)
                #pragma unroll
                for (int nf = 0; nf < 8; ++nf)
                    acc[mf][nf] = __builtin_amdgcn_mfma_f32_16x16x32_bf16(
                        af[mf], bfr[nf], acc[mf][nf], 0, 0, 0);
        }
    }

    // ---- epilogue: D row = gq*4+reg, col = ln15 (verified round 4) ----
    const int i0 = nb * 128;
    #pragma unroll
    for (int mf = 0; mf < 4; ++mf) {
        #pragma unroll
        for (int r = 0; r < 4; ++r) {
            const int mrow = gq * 4 + r;
            const int Mg_l = wave * 64 + mf * 16 + mrow;
            const int p = Mg_l & 7;
            if (p == 7) continue;                    // padded row
            const int bh_l = Mg_l >> 3;
            const int bhg = mb * 16 + bh_l;
            const int b = bhg / 7;
            const int h = bhg - 7 * b;
            #pragma unroll
            for (int nf = 0; nf < 8; ++nf) {
                const int i = i0 + nf * 16 + ln15;
                out[(((size_t)b * 512 + i) * 7 + h) * 7 + p] = acc[mf][nf][r];
            }
        }
    }
}

extern "C" void kernel_launch(void* const* d_in, const int* in_sizes, int n_in,
                              void* d_out, int out_size, void* d_ws, size_t ws_size,
                              hipStream_t stream) {
    const float* x  = (const float*)d_in[0];   // (1024,512,7,7) fp32
    const float* Wg = (const float*)d_in[1];   // (256,3,3,512) fp32
    float* out = (float*)d_out;                // (1024,512,7,7) fp32
    __bf16* W3 = (__bf16*)d_ws;                // 2304 frags x 1KB = 2.36 MB
    __bf16* Vt = (__bf16*)((char*)d_ws + VT_OFFSET);

    prep_w3<<<dim3(576), dim3(256), 0, stream>>>(Wg, W3);
    prep_vb<<<dim3(1024), dim3(256), 0, stream>>>(x, Vt);
    gemm_vt3<<<dim3(448 * 4), dim3(128), 0, stream>>>(Vt, W3, out);
}